// Round 20
// baseline (2197.660 us; speedup 1.0000x reference)
//
#include <hip/hip_runtime.h>
#include <hip/hip_bf16.h>
#include <cstdint>

#define NDIRS 16384
#define DMODEL 1024
#define BATCH 4096
#define KTOP 32
#define MKK 128
#define AUXK 256
#define DEADTHR 266
#define CAND_MAX 2048
// BLIS/AOCL-Zen sgemm K-blocking: KC=512 -> panels [0,512) [512,1024).
// K-step 8 -> fold after tile 63.
#define FOLD_T0 63

__device__ __forceinline__ unsigned fkey(float f) {
  unsigned u = __float_as_uint(f);
  return (u & 0x80000000u) ? ~u : (u | 0x80000000u);
}

// ---------------- xc = fl32(x - pre_bias), computed once ----------------
__global__ __launch_bounds__(256) void k_xc(const float* __restrict__ x,
                                            const float* __restrict__ pre_bias,
                                            float* __restrict__ xc) {
  const int i = (blockIdx.x * 256 + threadIdx.x) * 8;
  const int d = i & (DMODEL - 1);
  float4 a0 = *(const float4*)(x + i);
  float4 a1 = *(const float4*)(x + i + 4);
  const float4 p0 = *(const float4*)(pre_bias + d);
  const float4 p1 = *(const float4*)(pre_bias + d + 4);
  a0.x -= p0.x; a0.y -= p0.y; a0.z -= p0.z; a0.w -= p0.w;
  a1.x -= p1.x; a1.y -= p1.y; a1.z -= p1.z; a1.w -= p1.w;
  *(float4*)(xc + i) = a0;
  *(float4*)(xc + i + 4) = a1;
}

// ---------------- W_dec [DMODEL][NDIRS] -> WdT [NDIRS][DMODEL] ----------------
__global__ __launch_bounds__(256) void k_transpose(const float* __restrict__ Wdec,
                                                   float* __restrict__ WdT) {
  __shared__ float tile[32][33];
  const int tx = threadIdx.x & 31, ty = threadIdx.x >> 5;
  const int c0 = blockIdx.x * 32;
  const int r0 = blockIdx.y * 32;
#pragma unroll
  for (int i = 0; i < 32; i += 8)
    tile[ty + i][tx] = Wdec[(size_t)(r0 + ty + i) * NDIRS + c0 + tx];
  __syncthreads();
#pragma unroll
  for (int i = 0; i < 32; i += 8)
    WdT[(size_t)(c0 + ty + i) * DMODEL + r0 + tx] = tile[tx][ty + i];
}

// ---- P = xc @ Wenc^T + lb, BLIS/AOCL {512,512} K-panel rounding.
// K-step 8 variant of the R19-best structure: same 128x128 tile and 8x8
// micro-tile (preserves FMA:LDS-read ratio — R15 lesson), but LDS dbuf
// halves to 16.9 KB and staging regs halve -> VGPR ~110, allowing 4
// blocks/CU (16 waves) so barrier stalls are absorbed by other blocks
// (R19: 72% VALUBusy at 2 blocks/CU was the binding stall).
// bounds(256,2) — NEVER (256,4): caps VGPR at 64, FETCH x10 (R18).
template <bool XC>
__global__ __launch_bounds__(256, 2) void k_gemm_enc(
    const float* __restrict__ xA_src, const float* __restrict__ Wenc,
    const float* __restrict__ pre_bias, const float* __restrict__ lat_bias,
    float* __restrict__ P, float* __restrict__ latents_zero) {
  __shared__ __align__(16) float As[2][8][132];
  __shared__ __align__(16) float Bs[2][8][132];
  const int t = threadIdx.x;
  const int tx = t & 15, ty = t >> 4;
  const int bn = blockIdx.x;  // NDIRS/128
  const int bm = blockIdx.y;  // BATCH/128
  const int lr = t >> 1;        // 0..127 (staging row)
  const int lk = (t & 1) << 2;  // 0,4 (staging k)

  const float* xA = xA_src + (size_t)(bm * 128 + lr) * DMODEL;
  const float* wB = Wenc + (size_t)(bn * 128 + lr) * DMODEL;

  float acc[8][8];
#pragma unroll
  for (int i = 0; i < 8; ++i)
#pragma unroll
    for (int j = 0; j < 8; ++j) acc[i][j] = 0.f;

  const int c0 = bn * 128 + tx * 8;
  const int rdA = ty * 8;
  const int rdB = tx * 8;

  // stage tile 0
  float4 pb;
  if (!XC) pb = *(const float4*)(pre_bias + lk);
  float4 a0 = *(const float4*)(xA + lk);
  float4 b0 = *(const float4*)(wB + lk);

  int cur = 0;
  for (int tt = 0; tt < DMODEL / 8; ++tt) {
    // write staged tile into LDS[cur]
    if (XC) {
      As[cur][lk + 0][lr] = a0.x;
      As[cur][lk + 1][lr] = a0.y;
      As[cur][lk + 2][lr] = a0.z;
      As[cur][lk + 3][lr] = a0.w;
    } else {  // fp32 subtract first (reference xc rounding)
      As[cur][lk + 0][lr] = a0.x - pb.x;
      As[cur][lk + 1][lr] = a0.y - pb.y;
      As[cur][lk + 2][lr] = a0.z - pb.z;
      As[cur][lk + 3][lr] = a0.w - pb.w;
    }
    Bs[cur][lk + 0][lr] = b0.x;
    Bs[cur][lk + 1][lr] = b0.y;
    Bs[cur][lk + 2][lr] = b0.z;
    Bs[cur][lk + 3][lr] = b0.w;
    __syncthreads();
    // issue next tile's global loads; they fly under this tile's FMA block
    if (tt < DMODEL / 8 - 1) {
      const int k0 = (tt + 1) * 8;
      if (!XC) pb = *(const float4*)(pre_bias + k0 + lk);
      a0 = *(const float4*)(xA + k0 + lk);
      b0 = *(const float4*)(wB + k0 + lk);
    }
#pragma unroll
    for (int k = 0; k < 8; ++k) {
      float a[8], b[8];
      *(float4*)&a[0] = *(const float4*)&As[cur][k][rdA];
      *(float4*)&a[4] = *(const float4*)&As[cur][k][rdA + 4];
      *(float4*)&b[0] = *(const float4*)&Bs[cur][k][rdB];
      *(float4*)&b[4] = *(const float4*)&Bs[cur][k][rdB + 4];
#pragma unroll
      for (int i = 0; i < 8; ++i)
#pragma unroll
        for (int j = 0; j < 8; ++j) acc[i][j] = fmaf(a[i], b[j], acc[i][j]);
    }
    // BLIS K-panel boundary after k=512: park panel-0 partial in P, clear acc.
    if (tt == FOLD_T0) {
#pragma unroll
      for (int i = 0; i < 8; ++i) {
        const size_t ro = (size_t)(bm * 128 + ty * 8 + i) * NDIRS + c0;
        *(float4*)(P + ro) = *(float4*)&acc[i][0];
        *(float4*)(P + ro + 4) = *(float4*)&acc[i][4];
#pragma unroll
        for (int j = 0; j < 8; ++j) acc[i][j] = 0.f;
      }
    }
    cur ^= 1;
  }

  float lb8[8];
  *(float4*)&lb8[0] = *(const float4*)(lat_bias + c0);
  *(float4*)&lb8[4] = *(const float4*)(lat_bias + c0 + 4);
  const float4 z4 = make_float4(0.f, 0.f, 0.f, 0.f);
#pragma unroll
  for (int i = 0; i < 8; ++i) {
    const size_t ro = (size_t)(bm * 128 + ty * 8 + i) * NDIRS + c0;
    float p0[8];
    *(float4*)&p0[0] = *(const float4*)(P + ro);      // panel-0 partial
    *(float4*)&p0[4] = *(const float4*)(P + ro + 4);
    float o[8];
#pragma unroll
    for (int j = 0; j < 8; ++j) o[j] = (p0[j] + acc[i][j]) + lb8[j];
    *(float4*)(P + ro) = *(float4*)&o[0];
    *(float4*)(P + ro + 4) = *(float4*)&o[4];
    *(float4*)(latents_zero + ro) = z4;      // zero-fill latents here: hidden
    *(float4*)(latents_zero + ro + 4) = z4;  // under compute (R16 net win)
  }
}

// ---- per-row selection (single-sweep dual histogram) + fused sparse decode.
// 512 threads. Exact fp32-key rank, lower-index ties. latents pre-zeroed by
// GEMM -> scatter-only finale. ----
template <bool USET>
__global__ __launch_bounds__(512) void k_select_recons(
    const float* __restrict__ P, const int* __restrict__ stats,
    const float* __restrict__ Wd,  // USET ? WdT [N][D] : Wdec [D][N]
    const float* __restrict__ pre_bias,
    float* __restrict__ topk_v, float* __restrict__ topk_i,
    float* __restrict__ auxk_v, float* __restrict__ auxk_i,
    float* __restrict__ latents, float* __restrict__ recons,
    float* __restrict__ mrecons) {
  __shared__ unsigned histA[2048];
  __shared__ unsigned histD[2048];
  __shared__ unsigned chunk[256];
  __shared__ __align__(16) unsigned char uni[32768];  // pk hists, then cands
  __shared__ float sv[MKK];
  __shared__ int si[MKK];
  __shared__ unsigned cntA, cntD, sTa, sTd;

  unsigned (*pkA)[1024] = (unsigned(*)[1024])uni;            // 16 KB
  unsigned (*pkD)[1024] = (unsigned(*)[1024])(uni + 16384);  // 16 KB
  unsigned* candKeyA = (unsigned*)uni;                        // 8 KB
  unsigned short* candIdxA = (unsigned short*)(uni + 8192);   // 4 KB
  unsigned* candKeyD = (unsigned*)(uni + 12288);              // 8 KB
  unsigned short* candIdxD = (unsigned short*)(uni + 20480);  // 4 KB

  const int t = threadIdx.x;
  const int w = (t >> 6) & 3;  // 8 waves share 4 counter sets
  const int b = blockIdx.x;
  const float* rp = P + (size_t)b * NDIRS;

  // ---------- phase A: both histograms, one read of P+stats ----------
  for (int i = t; i < 8192; i += 512) ((unsigned*)uni)[i] = 0;
  if (t == 0) { cntA = 0; cntD = 0; sTa = 0; sTd = 0; }
  __syncthreads();
#pragma unroll
  for (int i = 0; i < 8; ++i) {
    const int e = (i * 512 + t) * 4;
    const float4 v = *(const float4*)(rp + e);
    const int4 s = *(const int4*)(stats + e);
    const float hv[4] = {v.x, v.y, v.z, v.w};
    const int sx[4] = {s.x, s.y, s.z, s.w};
#pragma unroll
    for (int c = 0; c < 4; ++c) {
      const unsigned bin = fkey(hv[c]) >> 21;
      const unsigned inc = 1u << ((bin & 1) << 4);
      atomicAdd(&pkA[w][bin >> 1], inc);
      if (sx[c] > DEADTHR && hv[c] > 0.f) atomicAdd(&pkD[w][bin >> 1], inc);
    }
  }
  __syncthreads();
  // ---------- phase B: merge + two threshold scans ----------
  for (int i = t; i < 2048; i += 512) {
    const int word = i >> 1, sh = (i & 1) << 4;
    unsigned sa = 0, sd = 0;
#pragma unroll
    for (int q = 0; q < 4; ++q) {
      sa += (pkA[q][word] >> sh) & 0xFFFFu;
      sd += (pkD[q][word] >> sh) & 0xFFFFu;
    }
    histA[i] = sa;
    histD[i] = sd;
  }
  __syncthreads();
  {  // scan A -> sTa
    if (t < 256) {
      unsigned cs = 0;
#pragma unroll
      for (int j = 0; j < 8; ++j) cs += histA[t * 8 + j];
      chunk[t] = cs;
    }
    __syncthreads();
    for (int s = 1; s < 256; s <<= 1) {
      unsigned add = (t < 256 && t + s < 256) ? chunk[t + s] : 0;
      __syncthreads();
      if (t < 256) chunk[t] += add;
      __syncthreads();
    }
    if (t < 256) {
      unsigned suf = (t + 1 < 256) ? chunk[t + 1] : 0;
      for (int j = 7; j >= 0; --j) {
        const unsigned h = histA[t * 8 + j];
        const unsigned ab = suf;
        suf += h;
        if (suf >= MKK && ab < MKK) sTa = (unsigned)(t * 8 + j);
      }
    }
  }
  __syncthreads();
  {  // scan D -> sTd
    if (t < 256) {
      unsigned cs = 0;
#pragma unroll
      for (int j = 0; j < 8; ++j) cs += histD[t * 8 + j];
      chunk[t] = cs;
    }
    __syncthreads();
    for (int s = 1; s < 256; s <<= 1) {
      unsigned add = (t < 256 && t + s < 256) ? chunk[t + s] : 0;
      __syncthreads();
      if (t < 256) chunk[t] += add;
      __syncthreads();
    }
    if (t < 256) {
      unsigned suf = (t + 1 < 256) ? chunk[t + 1] : 0;
      for (int j = 7; j >= 0; --j) {
        const unsigned h = histD[t * 8 + j];
        const unsigned ab = suf;
        suf += h;
        if (suf >= AUXK && ab < AUXK) sTd = (unsigned)(t * 8 + j);
      }
    }
  }
  __syncthreads();
  // ---------- phase C: both candidate lists, one read ----------
  {
    const unsigned Ta = sTa, Td = sTd;
#pragma unroll
    for (int i = 0; i < 8; ++i) {
      const int e = (i * 512 + t) * 4;
      const float4 v = *(const float4*)(rp + e);
      const int4 s = *(const int4*)(stats + e);
      const float hv[4] = {v.x, v.y, v.z, v.w};
      const int sx[4] = {s.x, s.y, s.z, s.w};
#pragma unroll
      for (int c = 0; c < 4; ++c) {
        const unsigned k = fkey(hv[c]);
        const unsigned bin = k >> 21;
        if (bin >= Ta) {
          unsigned p = atomicAdd(&cntA, 1u);
          if (p < CAND_MAX) { candKeyA[p] = k; candIdxA[p] = (unsigned short)(e + c); }
        }
        if (sx[c] > DEADTHR && hv[c] > 0.f && bin >= Td) {
          unsigned p = atomicAdd(&cntD, 1u);
          if (p < CAND_MAX) { candKeyD[p] = k; candIdxD[p] = (unsigned short)(e + c); }
        }
      }
    }
  }
  __syncthreads();
  // ---------- phase D: exact ranks ----------
  {
    const unsigned C = cntA < CAND_MAX ? cntA : CAND_MAX;
    for (unsigned i = t; i < C; i += 512) {
      const unsigned ki = candKeyA[i];
      const unsigned ii = candIdxA[i];
      unsigned r = 0;
      for (unsigned j = 0; j < C; ++j) {
        const unsigned kj = candKeyA[j];
        r += (unsigned)((kj > ki) | ((kj == ki) & (candIdxA[j] < ii)));
      }
      if (r < MKK) {
        const float vr = fmaxf(rp[ii], 0.f);
        sv[r] = vr;
        si[r] = (int)ii;
        if (r < KTOP) {
          topk_v[b * KTOP + r] = vr;
          topk_i[b * KTOP + r] = (float)ii;
        }
      }
    }
  }
  {
    const unsigned C = cntD < CAND_MAX ? cntD : CAND_MAX;
    for (unsigned i = t; i < C; i += 512) {
      const unsigned ki = candKeyD[i];
      const unsigned ii = candIdxD[i];
      unsigned r = 0;
      for (unsigned j = 0; j < C; ++j) {
        const unsigned kj = candKeyD[j];
        r += (unsigned)((kj > ki) | ((kj == ki) & (candIdxD[j] < ii)));
      }
      if (r < AUXK) {
        auxk_v[b * AUXK + r] = fmaxf(rp[ii], 0.f);
        auxk_i[b * AUXK + r] = (float)ii;
      }
    }
    if (t == 0 && C < AUXK) {  // not reachable with this data distribution
      for (unsigned r = C; r < AUXK; ++r) {
        auxk_v[b * AUXK + r] = 0.f;
        auxk_i[b * AUXK + r] = 0.f;
      }
    }
  }
  __syncthreads();
  // ---------- finale: scatter top-32 (latents pre-zeroed by GEMM) ----------
  if (t < KTOP) latents[(size_t)b * NDIRS + si[t]] = sv[t];
  // ---------- fused sparse decode (float2 per thread, 512 threads) ----------
  const int d = t * 2;
  float2 acc = *(const float2*)(pre_bias + d);
  if (USET) {
#pragma unroll 4
    for (int i = 0; i < KTOP; ++i) {
      const float v = sv[i];
      const float2 wv = *(const float2*)(Wd + (size_t)si[i] * DMODEL + d);
      acc.x = fmaf(v, wv.x, acc.x);
      acc.y = fmaf(v, wv.y, acc.y);
    }
    *(float2*)(recons + (size_t)b * DMODEL + d) = acc;
#pragma unroll 4
    for (int i = KTOP; i < MKK; ++i) {
      const float v = sv[i];
      const float2 wv = *(const float2*)(Wd + (size_t)si[i] * DMODEL + d);
      acc.x = fmaf(v, wv.x, acc.x);
      acc.y = fmaf(v, wv.y, acc.y);
    }
    *(float2*)(mrecons + (size_t)b * DMODEL + d) = acc;
  } else {
#pragma unroll 2
    for (int i = 0; i < MKK; ++i) {
      const float v = sv[i];
      const int j = si[i];
      acc.x = fmaf(v, Wd[(size_t)(d + 0) * NDIRS + j], acc.x);
      acc.y = fmaf(v, Wd[(size_t)(d + 1) * NDIRS + j], acc.y);
      if (i == KTOP - 1) *(float2*)(recons + (size_t)b * DMODEL + d) = acc;
    }
    *(float2*)(mrecons + (size_t)b * DMODEL + d) = acc;
  }
}

extern "C" void kernel_launch(void* const* d_in, const int* in_sizes, int n_in,
                              void* d_out, int out_size, void* d_ws,
                              size_t ws_size, hipStream_t stream) {
  const float* x = (const float*)d_in[0];
  const float* Wenc = (const float*)d_in[1];
  const float* Wdec = (const float*)d_in[2];
  const float* pre_bias = (const float*)d_in[3];
  const float* lat_bias = (const float*)d_in[4];
  const int* stats = (const int*)d_in[5];

  float* out = (float*)d_out;
  float* recons = out;
  float* mrecons = recons + (size_t)BATCH * DMODEL;
  float* topk_v = mrecons + (size_t)BATCH * DMODEL;
  float* topk_i = topk_v + (size_t)BATCH * KTOP;
  float* auxk_v = topk_i + (size_t)BATCH * KTOP;
  float* auxk_i = auxk_v + (size_t)BATCH * AUXK;
  float* P = auxk_i + (size_t)BATCH * AUXK;           // latents_pre_act
  float* latents = P + (size_t)BATCH * NDIRS;

  const size_t wdT_b = (size_t)NDIRS * DMODEL * sizeof(float);   // 64 MB
  const size_t xc_b = (size_t)BATCH * DMODEL * sizeof(float);    // 16 MB
  float* WdT = (float*)d_ws;
  float* xc = (float*)((char*)d_ws + wdT_b);
  const bool useT = ws_size >= wdT_b;
  const bool useXC = ws_size >= wdT_b + xc_b;

  if (useT) {
    dim3 g(NDIRS / 32, DMODEL / 32);
    k_transpose<<<g, 256, 0, stream>>>(Wdec, WdT);
  }
  if (useXC) {
    k_xc<<<BATCH * DMODEL / (256 * 8), 256, 0, stream>>>(x, pre_bias, xc);
    dim3 g(NDIRS / 128, BATCH / 128);
    k_gemm_enc<true><<<g, 256, 0, stream>>>(xc, Wenc, pre_bias, lat_bias, P,
                                            latents);
  } else {
    dim3 g(NDIRS / 128, BATCH / 128);
    k_gemm_enc<false><<<g, 256, 0, stream>>>(x, Wenc, pre_bias, lat_bias, P,
                                             latents);
  }
  if (useT)
    k_select_recons<true><<<BATCH, 512, 0, stream>>>(
        P, stats, WdT, pre_bias, topk_v, topk_i, auxk_v, auxk_i, latents,
        recons, mrecons);
  else
    k_select_recons<false><<<BATCH, 512, 0, stream>>>(
        P, stats, Wdec, pre_bias, topk_v, topk_i, auxk_v, auxk_i, latents,
        recons, mrecons);
}

// Round 21
// 2050.987 us; speedup vs baseline: 1.0715x; 1.0715x over previous
//
#include <hip/hip_runtime.h>
#include <hip/hip_bf16.h>
#include <cstdint>

#define NDIRS 16384
#define DMODEL 1024
#define BATCH 4096
#define KTOP 32
#define MKK 128
#define AUXK 256
#define DEADTHR 266
#define CAND_MAX 2048
// BLIS/AOCL-Zen sgemm K-blocking: KC=512 -> panels [0,512) [512,1024).
#define FOLD_T0 31

__device__ __forceinline__ unsigned fkey(float f) {
  unsigned u = __float_as_uint(f);
  return (u & 0x80000000u) ? ~u : (u | 0x80000000u);
}

// ---------------- xc = fl32(x - pre_bias), computed once ----------------
__global__ __launch_bounds__(256) void k_xc(const float* __restrict__ x,
                                            const float* __restrict__ pre_bias,
                                            float* __restrict__ xc) {
  const int i = (blockIdx.x * 256 + threadIdx.x) * 8;
  const int d = i & (DMODEL - 1);
  float4 a0 = *(const float4*)(x + i);
  float4 a1 = *(const float4*)(x + i + 4);
  const float4 p0 = *(const float4*)(pre_bias + d);
  const float4 p1 = *(const float4*)(pre_bias + d + 4);
  a0.x -= p0.x; a0.y -= p0.y; a0.z -= p0.z; a0.w -= p0.w;
  a1.x -= p1.x; a1.y -= p1.y; a1.z -= p1.z; a1.w -= p1.w;
  *(float4*)(xc + i) = a0;
  *(float4*)(xc + i + 4) = a1;
}

// ---------------- W_dec [DMODEL][NDIRS] -> WdT [NDIRS][DMODEL] ----------------
__global__ __launch_bounds__(256) void k_transpose(const float* __restrict__ Wdec,
                                                   float* __restrict__ WdT) {
  __shared__ float tile[32][33];
  const int tx = threadIdx.x & 31, ty = threadIdx.x >> 5;
  const int c0 = blockIdx.x * 32;
  const int r0 = blockIdx.y * 32;
#pragma unroll
  for (int i = 0; i < 32; i += 8)
    tile[ty + i][tx] = Wdec[(size_t)(r0 + ty + i) * NDIRS + c0 + tx];
  __syncthreads();
#pragma unroll
  for (int i = 0; i < 32; i += 8)
    WdT[(size_t)(c0 + ty + i) * DMODEL + r0 + tx] = tile[tx][ty + i];
}

// ---- P = xc @ Wenc^T + lb, BLIS/AOCL {512,512} K-panel rounding.
// R19 structure exactly (measured best, 2072us total; the full config-space
// ladder R9-R20 probed tile/K-step/threads/bounds/acc-layout and all
// alternatives regressed): 128x128 tile, 256 threads, 8x8 micro-tile, K-step
// 16, double-buffered LDS, one barrier/tile, register prefetch, panel-0
// parked in P, bounds(256,2) [VGPR cap 128 — NEVER (256,4): caps VGPR at 64,
// FETCH x10, R18]. XC: A from precomputed xc.
template <bool XC>
__global__ __launch_bounds__(256, 2) void k_gemm_enc(
    const float* __restrict__ xA_src, const float* __restrict__ Wenc,
    const float* __restrict__ pre_bias, const float* __restrict__ lat_bias,
    float* __restrict__ P, float* __restrict__ latents_zero) {
  __shared__ __align__(16) float As[2][16][132];
  __shared__ __align__(16) float Bs[2][16][132];
  const int t = threadIdx.x;
  const int tx = t & 15, ty = t >> 4;
  const int bn = blockIdx.x;  // NDIRS/128
  const int bm = blockIdx.y;  // BATCH/128
  const int lr = t >> 2;        // 0..63
  const int lk = (t & 3) << 2;  // 0,4,8,12

  const float* xA = xA_src + (size_t)(bm * 128 + lr) * DMODEL;
  const float* wB = Wenc + (size_t)(bn * 128 + lr) * DMODEL;

  float acc[8][8];
#pragma unroll
  for (int i = 0; i < 8; ++i)
#pragma unroll
    for (int j = 0; j < 8; ++j) acc[i][j] = 0.f;

  const int c0 = bn * 128 + tx * 8;
  const int rdA = ty * 8;
  const int rdB = tx * 8;

  // stage tile 0
  float4 pb;
  if (!XC) pb = *(const float4*)(pre_bias + lk);
  float4 a0 = *(const float4*)(xA + lk);
  float4 a1 = *(const float4*)(xA + (size_t)64 * DMODEL + lk);
  float4 b0 = *(const float4*)(wB + lk);
  float4 b1 = *(const float4*)(wB + (size_t)64 * DMODEL + lk);

  int cur = 0;
  for (int tt = 0; tt < DMODEL / 16; ++tt) {
    // write staged tile into LDS[cur]
    if (XC) {
      As[cur][lk + 0][lr] = a0.x;
      As[cur][lk + 1][lr] = a0.y;
      As[cur][lk + 2][lr] = a0.z;
      As[cur][lk + 3][lr] = a0.w;
      As[cur][lk + 0][lr + 64] = a1.x;
      As[cur][lk + 1][lr + 64] = a1.y;
      As[cur][lk + 2][lr + 64] = a1.z;
      As[cur][lk + 3][lr + 64] = a1.w;
    } else {  // fp32 subtract first (reference xc rounding)
      As[cur][lk + 0][lr] = a0.x - pb.x;
      As[cur][lk + 1][lr] = a0.y - pb.y;
      As[cur][lk + 2][lr] = a0.z - pb.z;
      As[cur][lk + 3][lr] = a0.w - pb.w;
      As[cur][lk + 0][lr + 64] = a1.x - pb.x;
      As[cur][lk + 1][lr + 64] = a1.y - pb.y;
      As[cur][lk + 2][lr + 64] = a1.z - pb.z;
      As[cur][lk + 3][lr + 64] = a1.w - pb.w;
    }
    Bs[cur][lk + 0][lr] = b0.x;  Bs[cur][lk + 1][lr] = b0.y;
    Bs[cur][lk + 2][lr] = b0.z;  Bs[cur][lk + 3][lr] = b0.w;
    Bs[cur][lk + 0][lr + 64] = b1.x;  Bs[cur][lk + 1][lr + 64] = b1.y;
    Bs[cur][lk + 2][lr + 64] = b1.z;  Bs[cur][lk + 3][lr + 64] = b1.w;
    __syncthreads();
    // issue next tile's global loads; they fly under this tile's FMA block
    if (tt < DMODEL / 16 - 1) {
      const int k0 = (tt + 1) * 16;
      if (!XC) pb = *(const float4*)(pre_bias + k0 + lk);
      a0 = *(const float4*)(xA + k0 + lk);
      a1 = *(const float4*)(xA + (size_t)64 * DMODEL + k0 + lk);
      b0 = *(const float4*)(wB + k0 + lk);
      b1 = *(const float4*)(wB + (size_t)64 * DMODEL + k0 + lk);
    }
#pragma unroll
    for (int k = 0; k < 16; ++k) {
      float a[8], b[8];
      *(float4*)&a[0] = *(const float4*)&As[cur][k][rdA];
      *(float4*)&a[4] = *(const float4*)&As[cur][k][rdA + 4];
      *(float4*)&b[0] = *(const float4*)&Bs[cur][k][rdB];
      *(float4*)&b[4] = *(const float4*)&Bs[cur][k][rdB + 4];
#pragma unroll
      for (int i = 0; i < 8; ++i)
#pragma unroll
        for (int j = 0; j < 8; ++j) acc[i][j] = fmaf(a[i], b[j], acc[i][j]);
    }
    // BLIS K-panel boundary after k=512: park panel-0 partial in P, clear acc.
    if (tt == FOLD_T0) {
#pragma unroll
      for (int i = 0; i < 8; ++i) {
        const size_t ro = (size_t)(bm * 128 + ty * 8 + i) * NDIRS + c0;
        *(float4*)(P + ro) = *(float4*)&acc[i][0];
        *(float4*)(P + ro + 4) = *(float4*)&acc[i][4];
#pragma unroll
        for (int j = 0; j < 8; ++j) acc[i][j] = 0.f;
      }
    }
    cur ^= 1;
  }

  float lb8[8];
  *(float4*)&lb8[0] = *(const float4*)(lat_bias + c0);
  *(float4*)&lb8[4] = *(const float4*)(lat_bias + c0 + 4);
  const float4 z4 = make_float4(0.f, 0.f, 0.f, 0.f);
#pragma unroll
  for (int i = 0; i < 8; ++i) {
    const size_t ro = (size_t)(bm * 128 + ty * 8 + i) * NDIRS + c0;
    float p0[8];
    *(float4*)&p0[0] = *(const float4*)(P + ro);      // panel-0 partial
    *(float4*)&p0[4] = *(const float4*)(P + ro + 4);
    float o[8];
#pragma unroll
    for (int j = 0; j < 8; ++j) o[j] = (p0[j] + acc[i][j]) + lb8[j];
    *(float4*)(P + ro) = *(float4*)&o[0];
    *(float4*)(P + ro + 4) = *(float4*)&o[4];
    *(float4*)(latents_zero + ro) = z4;      // zero-fill latents here: hidden
    *(float4*)(latents_zero + ro + 4) = z4;  // under compute (R16 net win)
  }
}

// ---- per-row selection (single-sweep dual histogram) + fused sparse decode.
// 512 threads. Exact fp32-key rank, lower-index ties. latents pre-zeroed by
// GEMM -> scatter-only finale. ----
template <bool USET>
__global__ __launch_bounds__(512) void k_select_recons(
    const float* __restrict__ P, const int* __restrict__ stats,
    const float* __restrict__ Wd,  // USET ? WdT [N][D] : Wdec [D][N]
    const float* __restrict__ pre_bias,
    float* __restrict__ topk_v, float* __restrict__ topk_i,
    float* __restrict__ auxk_v, float* __restrict__ auxk_i,
    float* __restrict__ latents, float* __restrict__ recons,
    float* __restrict__ mrecons) {
  __shared__ unsigned histA[2048];
  __shared__ unsigned histD[2048];
  __shared__ unsigned chunk[256];
  __shared__ __align__(16) unsigned char uni[32768];  // pk hists, then cands
  __shared__ float sv[MKK];
  __shared__ int si[MKK];
  __shared__ unsigned cntA, cntD, sTa, sTd;

  unsigned (*pkA)[1024] = (unsigned(*)[1024])uni;            // 16 KB
  unsigned (*pkD)[1024] = (unsigned(*)[1024])(uni + 16384);  // 16 KB
  unsigned* candKeyA = (unsigned*)uni;                        // 8 KB
  unsigned short* candIdxA = (unsigned short*)(uni + 8192);   // 4 KB
  unsigned* candKeyD = (unsigned*)(uni + 12288);              // 8 KB
  unsigned short* candIdxD = (unsigned short*)(uni + 20480);  // 4 KB

  const int t = threadIdx.x;
  const int w = (t >> 6) & 3;  // 8 waves share 4 counter sets
  const int b = blockIdx.x;
  const float* rp = P + (size_t)b * NDIRS;

  // ---------- phase A: both histograms, one read of P+stats ----------
  for (int i = t; i < 8192; i += 512) ((unsigned*)uni)[i] = 0;
  if (t == 0) { cntA = 0; cntD = 0; sTa = 0; sTd = 0; }
  __syncthreads();
#pragma unroll
  for (int i = 0; i < 8; ++i) {
    const int e = (i * 512 + t) * 4;
    const float4 v = *(const float4*)(rp + e);
    const int4 s = *(const int4*)(stats + e);
    const float hv[4] = {v.x, v.y, v.z, v.w};
    const int sx[4] = {s.x, s.y, s.z, s.w};
#pragma unroll
    for (int c = 0; c < 4; ++c) {
      const unsigned bin = fkey(hv[c]) >> 21;
      const unsigned inc = 1u << ((bin & 1) << 4);
      atomicAdd(&pkA[w][bin >> 1], inc);
      if (sx[c] > DEADTHR && hv[c] > 0.f) atomicAdd(&pkD[w][bin >> 1], inc);
    }
  }
  __syncthreads();
  // ---------- phase B: merge + two threshold scans ----------
  for (int i = t; i < 2048; i += 512) {
    const int word = i >> 1, sh = (i & 1) << 4;
    unsigned sa = 0, sd = 0;
#pragma unroll
    for (int q = 0; q < 4; ++q) {
      sa += (pkA[q][word] >> sh) & 0xFFFFu;
      sd += (pkD[q][word] >> sh) & 0xFFFFu;
    }
    histA[i] = sa;
    histD[i] = sd;
  }
  __syncthreads();
  {  // scan A -> sTa
    if (t < 256) {
      unsigned cs = 0;
#pragma unroll
      for (int j = 0; j < 8; ++j) cs += histA[t * 8 + j];
      chunk[t] = cs;
    }
    __syncthreads();
    for (int s = 1; s < 256; s <<= 1) {
      unsigned add = (t < 256 && t + s < 256) ? chunk[t + s] : 0;
      __syncthreads();
      if (t < 256) chunk[t] += add;
      __syncthreads();
    }
    if (t < 256) {
      unsigned suf = (t + 1 < 256) ? chunk[t + 1] : 0;
      for (int j = 7; j >= 0; --j) {
        const unsigned h = histA[t * 8 + j];
        const unsigned ab = suf;
        suf += h;
        if (suf >= MKK && ab < MKK) sTa = (unsigned)(t * 8 + j);
      }
    }
  }
  __syncthreads();
  {  // scan D -> sTd
    if (t < 256) {
      unsigned cs = 0;
#pragma unroll
      for (int j = 0; j < 8; ++j) cs += histD[t * 8 + j];
      chunk[t] = cs;
    }
    __syncthreads();
    for (int s = 1; s < 256; s <<= 1) {
      unsigned add = (t < 256 && t + s < 256) ? chunk[t + s] : 0;
      __syncthreads();
      if (t < 256) chunk[t] += add;
      __syncthreads();
    }
    if (t < 256) {
      unsigned suf = (t + 1 < 256) ? chunk[t + 1] : 0;
      for (int j = 7; j >= 0; --j) {
        const unsigned h = histD[t * 8 + j];
        const unsigned ab = suf;
        suf += h;
        if (suf >= AUXK && ab < AUXK) sTd = (unsigned)(t * 8 + j);
      }
    }
  }
  __syncthreads();
  // ---------- phase C: both candidate lists, one read ----------
  {
    const unsigned Ta = sTa, Td = sTd;
#pragma unroll
    for (int i = 0; i < 8; ++i) {
      const int e = (i * 512 + t) * 4;
      const float4 v = *(const float4*)(rp + e);
      const int4 s = *(const int4*)(stats + e);
      const float hv[4] = {v.x, v.y, v.z, v.w};
      const int sx[4] = {s.x, s.y, s.z, s.w};
#pragma unroll
      for (int c = 0; c < 4; ++c) {
        const unsigned k = fkey(hv[c]);
        const unsigned bin = k >> 21;
        if (bin >= Ta) {
          unsigned p = atomicAdd(&cntA, 1u);
          if (p < CAND_MAX) { candKeyA[p] = k; candIdxA[p] = (unsigned short)(e + c); }
        }
        if (sx[c] > DEADTHR && hv[c] > 0.f && bin >= Td) {
          unsigned p = atomicAdd(&cntD, 1u);
          if (p < CAND_MAX) { candKeyD[p] = k; candIdxD[p] = (unsigned short)(e + c); }
        }
      }
    }
  }
  __syncthreads();
  // ---------- phase D: exact ranks ----------
  {
    const unsigned C = cntA < CAND_MAX ? cntA : CAND_MAX;
    for (unsigned i = t; i < C; i += 512) {
      const unsigned ki = candKeyA[i];
      const unsigned ii = candIdxA[i];
      unsigned r = 0;
      for (unsigned j = 0; j < C; ++j) {
        const unsigned kj = candKeyA[j];
        r += (unsigned)((kj > ki) | ((kj == ki) & (candIdxA[j] < ii)));
      }
      if (r < MKK) {
        const float vr = fmaxf(rp[ii], 0.f);
        sv[r] = vr;
        si[r] = (int)ii;
        if (r < KTOP) {
          topk_v[b * KTOP + r] = vr;
          topk_i[b * KTOP + r] = (float)ii;
        }
      }
    }
  }
  {
    const unsigned C = cntD < CAND_MAX ? cntD : CAND_MAX;
    for (unsigned i = t; i < C; i += 512) {
      const unsigned ki = candKeyD[i];
      const unsigned ii = candIdxD[i];
      unsigned r = 0;
      for (unsigned j = 0; j < C; ++j) {
        const unsigned kj = candKeyD[j];
        r += (unsigned)((kj > ki) | ((kj == ki) & (candIdxD[j] < ii)));
      }
      if (r < AUXK) {
        auxk_v[b * AUXK + r] = fmaxf(rp[ii], 0.f);
        auxk_i[b * AUXK + r] = (float)ii;
      }
    }
    if (t == 0 && C < AUXK) {  // not reachable with this data distribution
      for (unsigned r = C; r < AUXK; ++r) {
        auxk_v[b * AUXK + r] = 0.f;
        auxk_i[b * AUXK + r] = 0.f;
      }
    }
  }
  __syncthreads();
  // ---------- finale: scatter top-32 (latents pre-zeroed by GEMM) ----------
  if (t < KTOP) latents[(size_t)b * NDIRS + si[t]] = sv[t];
  // ---------- fused sparse decode (float2 per thread, 512 threads) ----------
  const int d = t * 2;
  float2 acc = *(const float2*)(pre_bias + d);
  if (USET) {
#pragma unroll 4
    for (int i = 0; i < KTOP; ++i) {
      const float v = sv[i];
      const float2 wv = *(const float2*)(Wd + (size_t)si[i] * DMODEL + d);
      acc.x = fmaf(v, wv.x, acc.x);
      acc.y = fmaf(v, wv.y, acc.y);
    }
    *(float2*)(recons + (size_t)b * DMODEL + d) = acc;
#pragma unroll 4
    for (int i = KTOP; i < MKK; ++i) {
      const float v = sv[i];
      const float2 wv = *(const float2*)(Wd + (size_t)si[i] * DMODEL + d);
      acc.x = fmaf(v, wv.x, acc.x);
      acc.y = fmaf(v, wv.y, acc.y);
    }
    *(float2*)(mrecons + (size_t)b * DMODEL + d) = acc;
  } else {
#pragma unroll 2
    for (int i = 0; i < MKK; ++i) {
      const float v = sv[i];
      const int j = si[i];
      acc.x = fmaf(v, Wd[(size_t)(d + 0) * NDIRS + j], acc.x);
      acc.y = fmaf(v, Wd[(size_t)(d + 1) * NDIRS + j], acc.y);
      if (i == KTOP - 1) *(float2*)(recons + (size_t)b * DMODEL + d) = acc;
    }
    *(float2*)(mrecons + (size_t)b * DMODEL + d) = acc;
  }
}

extern "C" void kernel_launch(void* const* d_in, const int* in_sizes, int n_in,
                              void* d_out, int out_size, void* d_ws,
                              size_t ws_size, hipStream_t stream) {
  const float* x = (const float*)d_in[0];
  const float* Wenc = (const float*)d_in[1];
  const float* Wdec = (const float*)d_in[2];
  const float* pre_bias = (const float*)d_in[3];
  const float* lat_bias = (const float*)d_in[4];
  const int* stats = (const int*)d_in[5];

  float* out = (float*)d_out;
  float* recons = out;
  float* mrecons = recons + (size_t)BATCH * DMODEL;
  float* topk_v = mrecons + (size_t)BATCH * DMODEL;
  float* topk_i = topk_v + (size_t)BATCH * KTOP;
  float* auxk_v = topk_i + (size_t)BATCH * KTOP;
  float* auxk_i = auxk_v + (size_t)BATCH * AUXK;
  float* P = auxk_i + (size_t)BATCH * AUXK;           // latents_pre_act
  float* latents = P + (size_t)BATCH * NDIRS;

  const size_t wdT_b = (size_t)NDIRS * DMODEL * sizeof(float);   // 64 MB
  const size_t xc_b = (size_t)BATCH * DMODEL * sizeof(float);    // 16 MB
  float* WdT = (float*)d_ws;
  float* xc = (float*)((char*)d_ws + wdT_b);
  const bool useT = ws_size >= wdT_b;
  const bool useXC = ws_size >= wdT_b + xc_b;

  if (useT) {
    dim3 g(NDIRS / 32, DMODEL / 32);
    k_transpose<<<g, 256, 0, stream>>>(Wdec, WdT);
  }
  if (useXC) {
    k_xc<<<BATCH * DMODEL / (256 * 8), 256, 0, stream>>>(x, pre_bias, xc);
    dim3 g(NDIRS / 128, BATCH / 128);
    k_gemm_enc<true><<<g, 256, 0, stream>>>(xc, Wenc, pre_bias, lat_bias, P,
                                            latents);
  } else {
    dim3 g(NDIRS / 128, BATCH / 128);
    k_gemm_enc<false><<<g, 256, 0, stream>>>(x, Wenc, pre_bias, lat_bias, P,
                                             latents);
  }
  if (useT)
    k_select_recons<true><<<BATCH, 512, 0, stream>>>(
        P, stats, WdT, pre_bias, topk_v, topk_i, auxk_v, auxk_i, latents,
        recons, mrecons);
  else
    k_select_recons<false><<<BATCH, 512, 0, stream>>>(
        P, stats, Wdec, pre_bias, topk_v, topk_i, auxk_v, auxk_i, latents,
        recons, mrecons);
}